// Round 9
// baseline (47130.472 us; speedup 1.0000x reference)
//
#include <hip/hip_runtime.h>
#include <math.h>

#define NBLK 64
#define NT   256

constexpr int T1 = 33, NL = 6, VOC = 80;
constexpr float SQD = 22.62741699796952f;  // sqrt(512)

// ---------------- device state ----------------------------------------------
// memK/memV: R2 layout [l][b*256+m][512]
__device__ float g_memk[(size_t)NL * 2048 * 512];
__device__ float g_memv[(size_t)NL * 2048 * 512];
__device__ float g_kc[(size_t)NL * 8 * T1 * 512];   // self-attn K cache (PER LAYER)
__device__ float g_vc[(size_t)NL * 8 * T1 * 512];   // self-attn V cache (PER LAYER)
__device__ float g_att[8 * 512];
__device__ float g_y[8 * 512];
__device__ float g_h[8 * 2048];
__device__ int g_slots[NBLK * 32];  // one 128B line per block
__device__ int g_gflag[8 * 32];     // per-group flag, own line
__device__ int g_abort;

// ---------------- init: zero KV cache + barrier state ------------------------
__global__ void k_init() {
  const size_t n4 = (size_t)NL * 8 * T1 * 512 / 4;
  float4* a = (float4*)g_kc;
  float4* b = (float4*)g_vc;
  size_t i0 = (size_t)blockIdx.x * blockDim.x + threadIdx.x;
  float4 z{0.f, 0.f, 0.f, 0.f};
  for (size_t i = i0; i < n4; i += (size_t)gridDim.x * blockDim.x) { a[i] = z; b[i] = z; }
  if (blockIdx.x == 0) {
    for (int i = threadIdx.x; i < NBLK * 32; i += blockDim.x) g_slots[i] = 0;
    for (int i = threadIdx.x; i < 8 * 32; i += blockDim.x) g_gflag[i] = 0;
    if (threadIdx.x == 0) g_abort = 0;
  }
}

// ---------------- memK/memV precompute (EXACT R2/R7 code) --------------------
__global__ __launch_bounds__(256) void k_memkv(const float* __restrict__ mem,
                                               const float* __restrict__ caw,
                                               const float* __restrict__ cab) {
  __shared__ float mlds[128][34];
  __shared__ float wlds[256][34];
  const int tid = threadIdx.x;
  const int l = blockIdx.x / 64, rem = blockIdx.x % 64;
  const int mt = rem >> 2, rt = rem & 3;
  const float* wbase = caw + (size_t)l * 1536 * 512 + (size_t)512 * 512;

  float acc[8][16];
#pragma unroll
  for (int i = 0; i < 8; ++i)
#pragma unroll
    for (int j = 0; j < 16; ++j) acc[i][j] = 0.f;

  const int tm = tid >> 4, tr = tid & 15;

  for (int kb = 0; kb < 16; ++kb) {
    __syncthreads();
    {
      int row = tid >> 1, half = tid & 1;
      const float2* src = (const float2*)(mem + (size_t)(mt * 128 + row) * 512 + kb * 32 + half * 16);
      float2* dst = (float2*)&mlds[row][half * 16];
#pragma unroll
      for (int q = 0; q < 8; ++q) dst[q] = src[q];
    }
    {
      int c2 = (tid & 15) * 2, rb = tid >> 4;
#pragma unroll
      for (int q = 0; q < 16; ++q) {
        int row = rb + 16 * q;
        *(float2*)&wlds[row][c2] =
            *(const float2*)(wbase + (size_t)(rt * 256 + row) * 512 + kb * 32 + c2);
      }
    }
    __syncthreads();
#pragma unroll 4
    for (int k2 = 0; k2 < 16; ++k2) {
      float2 mv[8];
#pragma unroll
      for (int i = 0; i < 8; ++i) mv[i] = *(const float2*)&mlds[tm * 8 + i][2 * k2];
#pragma unroll
      for (int j = 0; j < 16; ++j) {
        float2 w2 = *(const float2*)&wlds[tr + 16 * j][2 * k2];
#pragma unroll
        for (int i = 0; i < 8; ++i) acc[i][j] += mv[i].x * w2.x + mv[i].y * w2.y;
      }
    }
  }
#pragma unroll
  for (int i = 0; i < 8; ++i) {
    int mrow = mt * 128 + tm * 8 + i;
#pragma unroll
    for (int j = 0; j < 16; ++j) {
      int r = rt * 256 + tr + 16 * j;
      float v = acc[i][j] + cab[l * 1536 + 512 + r];
      if (r < 512) g_memk[((size_t)l * 2048 + mrow) * 512 + r] = v;
      else         g_memv[((size_t)l * 2048 + mrow) * 512 + (r - 512)] = v;
    }
  }
}

// ---------------- per-group (8-block) barrier: release/acquire ---------------
__device__ __forceinline__ void bar(int e, int b, int h) {
  __syncthreads();
  if (h == 0) {
    if (threadIdx.x == 0)
      __hip_atomic_store(&g_slots[blockIdx.x * 32], e, __ATOMIC_RELEASE, __HIP_MEMORY_SCOPE_AGENT);
    if (threadIdx.x < 8) {
      int gd = 0;
      while (__hip_atomic_load(&g_slots[(b * 8 + threadIdx.x) * 32], __ATOMIC_RELAXED,
                               __HIP_MEMORY_SCOPE_AGENT) < e) {
        __builtin_amdgcn_s_sleep(1);
        if (++gd > (1 << 24)) { __hip_atomic_store(&g_abort, 1, __ATOMIC_RELAXED, __HIP_MEMORY_SCOPE_AGENT); break; }
        if ((gd & 4095) == 0 && __hip_atomic_load(&g_abort, __ATOMIC_RELAXED, __HIP_MEMORY_SCOPE_AGENT)) break;
      }
    }
    __builtin_amdgcn_fence(__ATOMIC_ACQUIRE, "agent");
    __syncthreads();
    if (threadIdx.x == 0)
      __hip_atomic_store(&g_gflag[b * 32], e, __ATOMIC_RELEASE, __HIP_MEMORY_SCOPE_AGENT);
  } else {
    if (threadIdx.x == 0) {
      __hip_atomic_store(&g_slots[blockIdx.x * 32], e, __ATOMIC_RELEASE, __HIP_MEMORY_SCOPE_AGENT);
      int gd = 0;
      while (__hip_atomic_load(&g_gflag[b * 32], __ATOMIC_RELAXED, __HIP_MEMORY_SCOPE_AGENT) < e) {
        __builtin_amdgcn_s_sleep(1);
        if (++gd > (1 << 24)) { __hip_atomic_store(&g_abort, 1, __ATOMIC_RELAXED, __HIP_MEMORY_SCOPE_AGENT); break; }
        if ((gd & 4095) == 0 && __hip_atomic_load(&g_abort, __ATOMIC_RELAXED, __HIP_MEMORY_SCOPE_AGENT)) break;
      }
      __builtin_amdgcn_fence(__ATOMIC_ACQUIRE, "agent");
    }
    __syncthreads();
  }
}

// ---------------- 8-value x 64-lane butterfly reduce (EXACT R2) --------------
__device__ __forceinline__ float wave_reduce8(const float (&acc)[8], int lane) {
  float a0, a1, a2, a3;
  {
    bool hi = lane & 1;
    float s0 = hi ? acc[0] : acc[1], s1 = hi ? acc[2] : acc[3];
    float s2 = hi ? acc[4] : acc[5], s3 = hi ? acc[6] : acc[7];
    float r0 = __shfl_xor(s0, 1), r1 = __shfl_xor(s1, 1);
    float r2 = __shfl_xor(s2, 1), r3 = __shfl_xor(s3, 1);
    a0 = (hi ? acc[1] : acc[0]) + r0;  a1 = (hi ? acc[3] : acc[2]) + r1;
    a2 = (hi ? acc[5] : acc[4]) + r2;  a3 = (hi ? acc[7] : acc[6]) + r3;
  }
  float b0, b1;
  {
    bool hi = lane & 2;
    float s0 = hi ? a0 : a1, s1 = hi ? a2 : a3;
    float r0 = __shfl_xor(s0, 2), r1 = __shfl_xor(s1, 2);
    b0 = (hi ? a1 : a0) + r0;  b1 = (hi ? a3 : a2) + r1;
  }
  float f;
  {
    bool hi = lane & 4;
    float s = hi ? b0 : b1;
    float r = __shfl_xor(s, 4);
    f = (hi ? b1 : b0) + r;
  }
  f += __shfl_xor(f, 8);  f += __shfl_xor(f, 16);  f += __shfl_xor(f, 32);
  return f;
}

// ---------------- persistent decode kernel ----------------------------------
struct DecP {
  const float *mem, *emb, *pe, *saw, *sab, *sow, *sob, *caw, *cab, *cow, *cob,
              *lnw, *lnb, *f1w, *f1b, *f2w, *f2b, *cw, *cb;
  float* out;
};

__global__ __launch_bounds__(NT) void k_decode(DecP P) {
  __shared__ float s_x[512];    // layer input x (residual for C); embedding
  __shared__ float s_x2[512];   // LN(l,0)(y)   (residual for F)
  __shared__ float s_x3[512];   // LN(l,1)(y2)  (residual for H)
  __shared__ float s_yv[512];   // staged exchange vector
  __shared__ float s_a[512];    // attention vector staging
  __shared__ float s_hf[2048];  // FF1 output (full)
  __shared__ float s_q[64];
  __shared__ float s_p[336];
  __shared__ float s_w[4][2];
  __shared__ float s_pv[4][64];
  __shared__ int   s_tok[T1];
  __shared__ int   s_int[1];

  const int tid = threadIdx.x, bid = blockIdx.x;
  const int lane = tid & 63, wv = tid >> 6;
  const int b = bid >> 3, h = bid & 7;
  int e = 0;

  // LayerNorm, EXACT R2 stage_in expression shape (one wave, redundant per block)
  auto ln_wave = [&](const float* src, float* dst, const float* lw, const float* lb) {
    if (wv == 0) {
      float vals[8]; float sm = 0.f;
#pragma unroll
      for (int j = 0; j < 8; ++j) { vals[j] = src[lane + 64 * j]; sm += vals[j]; }
#pragma unroll
      for (int o = 32; o; o >>= 1) sm += __shfl_xor(sm, o);
      float mu = sm * (1.f / 512.f);
      float s2 = 0.f;
#pragma unroll
      for (int j = 0; j < 8; ++j) { float d = vals[j] - mu; s2 += d * d; }
#pragma unroll
      for (int o = 32; o; o >>= 1) s2 += __shfl_xor(s2, o);
      float rstd = 1.f / sqrtf(s2 * (1.f / 512.f) + 1e-5f);
#pragma unroll
      for (int j = 0; j < 8; ++j) {
        int c = lane + 64 * j;
        dst[c] = (vals[j] - mu) * rstd * lw[c] + lb[c];
      }
    }
    __syncthreads();
  };

  auto load512 = [&](float* dst, const float* src) {
    float2 v = *(const float2*)(src + tid * 2);
    dst[tid * 2] = v.x; dst[tid * 2 + 1] = v.y;
    __syncthreads();
  };

  // init embedding
  for (int c = tid; c < 512; c += 256) s_x[c] = P.pe[c] + P.emb[2 * 512 + c] * SQD;
  if (tid == 0) s_tok[0] = 2;
  __syncthreads();

  for (int t = 0; t < 32; ++t) {
    for (int l = 0; l < NL; ++l) {
      // ==== A: QKV for head h (rows sec*512 + h*64 + dd), full-512 dots ====
      {
        const float* Wl = P.saw + (size_t)l * 1536 * 512;
        const float* Bl = P.sab + l * 1536;
#pragma unroll 2
        for (int it = 0; it < 6; ++it) {
          int u0 = it * 32 + wv * 8;
          float acc[8];
#pragma unroll
          for (int i = 0; i < 8; ++i) {
            int u = u0 + i, sec = u >> 6, dd = u & 63;
            const float* wr = Wl + (size_t)(sec * 512 + h * 64 + dd) * 512;
            float a = 0.f;
#pragma unroll
            for (int j = 0; j < 8; ++j) a += wr[lane + 64 * j] * s_x[lane + 64 * j];
            acc[i] = a;
          }
          float f = wave_reduce8(acc, lane);
          if (lane < 8) {
            int u = u0 + lane, sec = u >> 6, dd = u & 63;
            float v = f + Bl[sec * 512 + h * 64 + dd];
            if (sec == 0) s_q[dd] = v;
            else if (sec == 1) g_kc[(((size_t)l * 8 + b) * T1 + t) * 512 + h * 64 + dd] = v;
            else               g_vc[(((size_t)l * 8 + b) * T1 + t) * 512 + h * 64 + dd] = v;
          }
        }
      }
      __syncthreads();

      // ==== B: self-attention (EXACT R2 expression shapes, per-layer KV) ====
      if (wv == 0) {
        float sc = -3.4e38f;
        if (lane <= t) {
          const float4* kr = (const float4*)&g_kc[(((size_t)l * 8 + b) * T1 + lane) * 512 + h * 64];
          float s = 0.f;
#pragma unroll
          for (int d4 = 0; d4 < 16; ++d4) {
            float4 kv = kr[d4];
            s += s_q[d4 * 4 + 0] * kv.x + s_q[d4 * 4 + 1] * kv.y +
                 s_q[d4 * 4 + 2] * kv.z + s_q[d4 * 4 + 3] * kv.w;
          }
          sc = s * 0.125f;
        }
        float m = sc;
#pragma unroll
        for (int o = 32; o; o >>= 1) m = fmaxf(m, __shfl_xor(m, o));
        float ex = (lane <= t) ? expf(sc - m) : 0.f;
        float sum = ex;
#pragma unroll
        for (int o = 32; o; o >>= 1) sum += __shfl_xor(sum, o);
        s_p[64 + lane] = ex / sum;
        asm volatile("s_waitcnt lgkmcnt(0)" ::: "memory");
        __builtin_amdgcn_sched_barrier(0);
        const float* vb = &g_vc[(((size_t)l * 8 + b) * T1) * 512 + h * 64 + lane];
        float o1 = 0.f, o2 = 0.f;
#pragma unroll
        for (int j = 0; j < 16; ++j) o1 += s_p[64 + j] * vb[(size_t)j * 512];
#pragma unroll
        for (int j = 16; j < 32; ++j) o2 += s_p[64 + j] * vb[(size_t)j * 512];
        g_att[b * 512 + h * 64 + lane] = o1 + o2;
      }
      bar(++e, b, h);

      // ==== C: self out-proj rows [h*64,+64), full-512, + residual(s_x) ====
      load512(s_a, g_att + b * 512);
      {
        const float* Wo = P.sow + (size_t)l * 512 * 512;
        const float* Bo = P.sob + l * 512;
#pragma unroll
        for (int it = 0; it < 2; ++it) {
          int r0l = it * 32 + wv * 8;
          float acc[8];
#pragma unroll
          for (int i = 0; i < 8; ++i) {
            const float* wr = Wo + (size_t)(h * 64 + r0l + i) * 512;
            float a = 0.f;
#pragma unroll
            for (int j = 0; j < 8; ++j) a += wr[lane + 64 * j] * s_a[lane + 64 * j];
            acc[i] = a;
          }
          float f = wave_reduce8(acc, lane);
          if (lane < 8) {
            int r = h * 64 + r0l + lane;
            float v = f + Bo[r];
            g_y[b * 512 + r] = v + s_x[r];
          }
        }
      }
      bar(++e, b, h);

      // ==== D: LN(l,0) + cross-attn Q rows [h*64,+64) ====
      load512(s_yv, g_y + b * 512);
      ln_wave(s_yv, s_x2, P.lnw + (l * 3 + 0) * 512, P.lnb + (l * 3 + 0) * 512);
      {
        const float* Wq = P.caw + (size_t)l * 1536 * 512;
        const float* Bq = P.cab + l * 1536;
#pragma unroll
        for (int it = 0; it < 2; ++it) {
          int r0l = it * 32 + wv * 8;
          float acc[8];
#pragma unroll
          for (int i = 0; i < 8; ++i) {
            const float* wr = Wq + (size_t)(h * 64 + r0l + i) * 512;
            float a = 0.f;
#pragma unroll
            for (int j = 0; j < 8; ++j) a += wr[lane + 64 * j] * s_x2[lane + 64 * j];
            acc[i] = a;
          }
          float f = wave_reduce8(acc, lane);
          if (lane < 8) s_q[r0l + lane] = f + Bq[h * 64 + r0l + lane];
        }
      }
      __syncthreads();

      // ==== E: cross-attention over 256 memory keys (EXACT R2) ====
      {
        int m0 = wv * 64 + lane;
        const float4* kr = (const float4*)&g_memk[((size_t)l * 2048 + b * 256 + m0) * 512 + h * 64];
        float s = 0.f;
#pragma unroll
        for (int d4 = 0; d4 < 16; ++d4) {
          float4 kv = kr[d4];
          s += s_q[d4 * 4 + 0] * kv.x + s_q[d4 * 4 + 1] * kv.y +
               s_q[d4 * 4 + 2] * kv.z + s_q[d4 * 4 + 3] * kv.w;
        }
        s *= 0.125f;
        float m = s;
#pragma unroll
        for (int o = 32; o; o >>= 1) m = fmaxf(m, __shfl_xor(m, o));
        if (lane == 0) s_w[wv][0] = m;
        __syncthreads();
        float M = fmaxf(fmaxf(s_w[0][0], s_w[1][0]), fmaxf(s_w[2][0], s_w[3][0]));
        float ex = expf(s - M);
        float sum = ex;
#pragma unroll
        for (int o = 32; o; o >>= 1) sum += __shfl_xor(sum, o);
        if (lane == 0) s_w[wv][1] = sum;
        __syncthreads();
        float S = s_w[0][1] + s_w[1][1] + s_w[2][1] + s_w[3][1];
        s_p[64 + m0] = ex / S;
        __syncthreads();
        const float* vbase = &g_memv[((size_t)l * 2048 + b * 256) * 512 + h * 64];
        float o1 = 0.f, o2 = 0.f;
#pragma unroll 8
        for (int j = 0; j < 32; ++j) {
          int mm = wv * 64 + j;
          o1 += s_p[64 + mm] * vbase[(size_t)mm * 512 + lane];
        }
#pragma unroll 8
        for (int j = 32; j < 64; ++j) {
          int mm = wv * 64 + j;
          o2 += s_p[64 + mm] * vbase[(size_t)mm * 512 + lane];
        }
        s_pv[wv][lane] = o1 + o2;
        __syncthreads();
        if (wv == 0) {
          float tot = s_pv[0][lane] + s_pv[1][lane] + s_pv[2][lane] + s_pv[3][lane];
          g_att[b * 512 + h * 64 + lane] = tot;
        }
      }
      bar(++e, b, h);

      // ==== F: cross out-proj rows [h*64,+64) + residual(s_x2) ====
      load512(s_a, g_att + b * 512);
      {
        const float* Wo = P.cow + (size_t)l * 512 * 512;
        const float* Bo = P.cob + l * 512;
#pragma unroll
        for (int it = 0; it < 2; ++it) {
          int r0l = it * 32 + wv * 8;
          float acc[8];
#pragma unroll
          for (int i = 0; i < 8; ++i) {
            const float* wr = Wo + (size_t)(h * 64 + r0l + i) * 512;
            float a = 0.f;
#pragma unroll
            for (int j = 0; j < 8; ++j) a += wr[lane + 64 * j] * s_a[lane + 64 * j];
            acc[i] = a;
          }
          float f = wave_reduce8(acc, lane);
          if (lane < 8) {
            int r = h * 64 + r0l + lane;
            float v = f + Bo[r];
            g_y[b * 512 + r] = v + s_x2[r];
          }
        }
      }
      bar(++e, b, h);

      // ==== G: LN(l,1) + FF1 rows [h*256,+256) + GELU ====
      load512(s_yv, g_y + b * 512);
      ln_wave(s_yv, s_x3, P.lnw + (l * 3 + 1) * 512, P.lnb + (l * 3 + 1) * 512);
      {
        const float* W1 = P.f1w + (size_t)l * 2048 * 512;
        const float* B1 = P.f1b + l * 2048;
#pragma unroll 2
        for (int it = 0; it < 8; ++it) {
          int r0l = it * 32 + wv * 8;
          float acc[8];
#pragma unroll
          for (int i = 0; i < 8; ++i) {
            const float* wr = W1 + (size_t)(h * 256 + r0l + i) * 512;
            float a = 0.f;
#pragma unroll
            for (int j = 0; j < 8; ++j) a += wr[lane + 64 * j] * s_x3[lane + 64 * j];
            acc[i] = a;
          }
          float f = wave_reduce8(acc, lane);
          if (lane < 8) {
            int r = h * 256 + r0l + lane;
            float v = f + B1[r];
            g_h[b * 2048 + r] = 0.5f * v * (1.f + erff(v * 0.70710678118654752f));
          }
        }
      }
      bar(++e, b, h);

      // ==== H: FF2 rows [h*64,+64), full-2048, + residual(s_x3) ====
      {
        const float* src = g_h + b * 2048 + tid * 2;
        float2 v0 = *(const float2*)(src);
        float2 v1 = *(const float2*)(src + 512);
        float2 v2 = *(const float2*)(src + 1024);
        float2 v3 = *(const float2*)(src + 1536);
        s_hf[tid * 2] = v0.x;        s_hf[tid * 2 + 1] = v0.y;
        s_hf[tid * 2 + 512] = v1.x;  s_hf[tid * 2 + 513] = v1.y;
        s_hf[tid * 2 + 1024] = v2.x; s_hf[tid * 2 + 1025] = v2.y;
        s_hf[tid * 2 + 1536] = v3.x; s_hf[tid * 2 + 1537] = v3.y;
      }
      __syncthreads();
      {
        const float* W2 = P.f2w + (size_t)l * 512 * 2048;
        const float* B2 = P.f2b + l * 512;
#pragma unroll
        for (int it = 0; it < 2; ++it) {
          int r0l = it * 32 + wv * 8;
          float acc[8];
#pragma unroll
          for (int i = 0; i < 8; ++i) {
            const float* wr = W2 + (size_t)(h * 64 + r0l + i) * 2048;
            float a = 0.f;
#pragma unroll 8
            for (int j = 0; j < 32; ++j) a += wr[lane + 64 * j] * s_hf[lane + 64 * j];
            acc[i] = a;
          }
          float f = wave_reduce8(acc, lane);
          if (lane < 8) {
            int r = h * 64 + r0l + lane;
            g_y[b * 512 + r] = f + B2[r] + s_x3[r];
          }
        }
      }
      bar(++e, b, h);

      // ==== deferred LN(l,2) -> s_x for next layer / CLF (local, no barrier) ====
      load512(s_yv, g_y + b * 512);
      ln_wave(s_yv, s_x, P.lnw + (l * 3 + 2) * 512, P.lnb + (l * 3 + 2) * 512);
    }

    // ==== CLF: logits (80 rows, redundant per block) from s_x = LN(5,2)(y) ====
    for (int i = 0; i < 20; ++i) {
      int r = wv * 20 + i;
      const float* wr = P.cw + (size_t)r * 512;
      float a = 0.f;
#pragma unroll
      for (int j = 0; j < 8; ++j) a += wr[lane + 64 * j] * s_x[lane + 64 * j];
#pragma unroll
      for (int o = 32; o; o >>= 1) a += __shfl_xor(a, o);
      if (lane == 0) {
        float v = a + P.cb[r];
        s_p[r] = v;
        if (h == 0) P.out[((size_t)b * 32 + t) * VOC + r] = v;
      }
    }
    __syncthreads();

    // ==== ARG: argmax (first-max) + next-token embedding (all local) ====
    if (wv == 0) {
      float v1 = s_p[lane];
      int i1 = lane;
      if (lane < 16) {
        float v2 = s_p[64 + lane];
        if (v2 > v1) { v1 = v2; i1 = 64 + lane; }
      }
#pragma unroll
      for (int o = 32; o; o >>= 1) {
        float ov = __shfl_xor(v1, o);
        int oi = __shfl_xor(i1, o);
        if (ov > v1 || (ov == v1 && oi < i1)) { v1 = ov; i1 = oi; }
      }
      if (lane == 0) s_int[0] = i1;
    }
    __syncthreads();
    {
      int pred = s_int[0];
      if (tid == 0) s_tok[t + 1] = pred;
      for (int c = tid; c < 512; c += 256)
        s_x[c] = P.pe[(t + 2) * 512 + c] + P.emb[(size_t)pred * 512 + c] * SQD;
    }
    __syncthreads();
  }

  // ---- sampled output: [SOS, preds...], PAD through first EOS (or idx 0) ----
  if (h == 0 && tid == 0) {
    int eos = -1;
    for (int j = 0; j < T1; ++j)
      if (s_tok[j] == 1 && eos < 0) eos = j;
    if (eos < 0) eos = 0;
    for (int j = 0; j < T1; ++j)
      P.out[20480 + b * T1 + j] = (j <= eos) ? 0.f : (float)s_tok[j];
  }
}

// ---------------- host entry -------------------------------------------------
extern "C" void kernel_launch(void* const* d_in, const int* in_sizes, int n_in,
                              void* d_out, int out_size, void* d_ws, size_t ws_size,
                              hipStream_t stream) {
  (void)in_sizes; (void)n_in; (void)d_ws; (void)ws_size; (void)out_size;
  const float* mem = (const float*)d_in[0];
  const float* emb = (const float*)d_in[1];
  const float* pe  = (const float*)d_in[2];
  const float* saw = (const float*)d_in[3];
  const float* sab = (const float*)d_in[4];
  const float* sow = (const float*)d_in[5];
  const float* sob = (const float*)d_in[6];
  const float* caw = (const float*)d_in[7];
  const float* cab = (const float*)d_in[8];
  const float* cow = (const float*)d_in[9];
  const float* cob = (const float*)d_in[10];
  const float* lnw = (const float*)d_in[11];
  const float* lnb = (const float*)d_in[12];
  const float* f1w = (const float*)d_in[13];
  const float* f1b = (const float*)d_in[14];
  const float* f2w = (const float*)d_in[15];
  const float* f2b = (const float*)d_in[16];
  const float* cw  = (const float*)d_in[17];
  const float* cb  = (const float*)d_in[18];

  hipLaunchKernelGGL(k_init, dim3(256), dim3(256), 0, stream);
  hipLaunchKernelGGL(k_memkv, dim3(384), dim3(256), 0, stream, mem, caw, cab);
  DecP P{mem, emb, pe, saw, sab, sow, sob, caw, cab, cow, cob,
         lnw, lnb, f1w, f1b, f2w, f2b, cw, cb, (float*)d_out};
  hipLaunchKernelGGL(k_decode, dim3(NBLK), dim3(NT), 0, stream, P);
}

// Round 10
// 25228.403 us; speedup vs baseline: 1.8682x; 1.8682x over previous
//
#include <hip/hip_runtime.h>
#include <math.h>

#define NBLK 64
#define NT   256

constexpr int D = 512, T1 = 33, NL = 6, VOC = 80;
constexpr float SQD = 22.62741699796952f;  // sqrt(512)

typedef float vf4 __attribute__((ext_vector_type(4)));

// ---------------- device state (fully rewritten every call) ----------------
__device__ __align__(16) float g_memk[(size_t)NL * 2048 * 512];
__device__ __align__(16) float g_memv[(size_t)NL * 2048 * 512];
__device__ __align__(16) float g_kc[(size_t)NL * 8 * T1 * 512];
__device__ __align__(16) float g_vc[(size_t)NL * 8 * T1 * 512];
__device__ __align__(16) float g_x[8 * 512], g_x2[8 * 512], g_y[8 * 512], g_q[8 * 512], g_att[8 * 512];
__device__ __align__(16) float g_h[8 * 2048];
__device__ __align__(16) float g_logits[8 * VOC];
__device__ int   g_tok[8 * T1];
__device__ int   g_slots[NBLK];
__device__ int   g_phase;
__device__ int   g_abort;

// ---------------- sc0 sc1 (MALL write-through / bypass) accessors -----------
__device__ __forceinline__ void st_sc(float* p, float v) {
  asm volatile("global_store_dword %0, %1, off sc0 sc1" :: "v"(p), "v"(v) : "memory");
}
__device__ __forceinline__ void st4_sc(float* p, vf4 v) {
  asm volatile("global_store_dwordx4 %0, %1, off sc0 sc1" :: "v"(p), "v"(v) : "memory");
}
__device__ __forceinline__ void st_sci(int* p, int v) {
  asm volatile("global_store_dword %0, %1, off sc0 sc1" :: "v"(p), "v"(v) : "memory");
}
__device__ __forceinline__ float ld_sc(const float* p) {
  float r;
  asm volatile("global_load_dword %0, %1, off sc0 sc1\n\ts_waitcnt vmcnt(0)"
               : "=&v"(r) : "v"(p) : "memory");
  return r;
}
__device__ __forceinline__ int ld_sci(const int* p) {
  int r;
  asm volatile("global_load_dword %0, %1, off sc0 sc1\n\ts_waitcnt vmcnt(0)"
               : "=&v"(r) : "v"(p) : "memory");
  return r;
}
// 4x dwordx4 batched loads, single waitcnt (pipelined MALL reads)
__device__ __forceinline__ void ld4x4_sc(const float* p0, const float* p1,
                                         const float* p2, const float* p3,
                                         vf4& a, vf4& b, vf4& c, vf4& d) {
  asm volatile(
      "global_load_dwordx4 %0, %4, off sc0 sc1\n\t"
      "global_load_dwordx4 %1, %5, off sc0 sc1\n\t"
      "global_load_dwordx4 %2, %6, off sc0 sc1\n\t"
      "global_load_dwordx4 %3, %7, off sc0 sc1\n\t"
      "s_waitcnt vmcnt(0)"
      : "=&v"(a), "=&v"(b), "=&v"(c), "=&v"(d)
      : "v"(p0), "v"(p1), "v"(p2), "v"(p3) : "memory");
}

// ---------------- init kernel (reset barrier state each call) --------------
__global__ void k_init() {
  if (threadIdx.x < NBLK) g_slots[threadIdx.x] = 0;
  if (threadIdx.x == 0) { g_phase = 0; g_abort = 0; }
}

// ---------------- memK/memV precompute (EXACT R2/R7 code) ------------------
__global__ __launch_bounds__(256) void k_memkv(const float* __restrict__ mem,
                                               const float* __restrict__ caw,
                                               const float* __restrict__ cab) {
  __shared__ float mlds[128][34];
  __shared__ float wlds[256][34];
  const int tid = threadIdx.x;
  const int l = blockIdx.x / 64, rem = blockIdx.x % 64;
  const int mt = rem >> 2, rt = rem & 3;
  const float* wbase = caw + (size_t)l * 1536 * 512 + (size_t)512 * 512;

  float acc[8][16];
#pragma unroll
  for (int i = 0; i < 8; ++i)
#pragma unroll
    for (int j = 0; j < 16; ++j) acc[i][j] = 0.f;

  const int tm = tid >> 4, tr = tid & 15;

  for (int kb = 0; kb < 16; ++kb) {
    __syncthreads();
    {
      int row = tid >> 1, half = tid & 1;
      const float2* src = (const float2*)(mem + (size_t)(mt * 128 + row) * 512 + kb * 32 + half * 16);
      float2* dst = (float2*)&mlds[row][half * 16];
#pragma unroll
      for (int q = 0; q < 8; ++q) dst[q] = src[q];
    }
    {
      int c2 = (tid & 15) * 2, rb = tid >> 4;
#pragma unroll
      for (int q = 0; q < 16; ++q) {
        int row = rb + 16 * q;
        *(float2*)&wlds[row][c2] =
            *(const float2*)(wbase + (size_t)(rt * 256 + row) * 512 + kb * 32 + c2);
      }
    }
    __syncthreads();
#pragma unroll 4
    for (int k2 = 0; k2 < 16; ++k2) {
      float2 mv[8];
#pragma unroll
      for (int i = 0; i < 8; ++i) mv[i] = *(const float2*)&mlds[tm * 8 + i][2 * k2];
#pragma unroll
      for (int j = 0; j < 16; ++j) {
        float2 w2 = *(const float2*)&wlds[tr + 16 * j][2 * k2];
#pragma unroll
        for (int i = 0; i < 8; ++i) acc[i][j] += mv[i].x * w2.x + mv[i].y * w2.y;
      }
    }
  }
#pragma unroll
  for (int i = 0; i < 8; ++i) {
    int mrow = mt * 128 + tm * 8 + i;
#pragma unroll
    for (int j = 0; j < 16; ++j) {
      int r = rt * 256 + tr + 16 * j;
      float v = acc[i][j] + cab[l * 1536 + 512 + r];
      if (r < 512) g_memk[((size_t)l * 2048 + mrow) * 512 + r] = v;
      else         g_memv[((size_t)l * 2048 + mrow) * 512 + (r - 512)] = v;
    }
  }
}

// ---------------- grid barrier: relaxed flags, NO fences (data goes sc) -----
__device__ __forceinline__ void gbar(int e) {
  asm volatile("s_waitcnt vmcnt(0) lgkmcnt(0)" ::: "memory");
  __syncthreads();
  if (blockIdx.x == 0) {
    if (threadIdx.x == 0)
      __hip_atomic_store(&g_slots[0], e, __ATOMIC_RELAXED, __HIP_MEMORY_SCOPE_AGENT);
    if (threadIdx.x < NBLK) {
      int i = threadIdx.x, gd = 0;
      while (__hip_atomic_load(&g_slots[i], __ATOMIC_RELAXED, __HIP_MEMORY_SCOPE_AGENT) < e) {
        __builtin_amdgcn_s_sleep(1);
        if (++gd > (1 << 24)) { __hip_atomic_store(&g_abort, 1, __ATOMIC_RELAXED, __HIP_MEMORY_SCOPE_AGENT); break; }
        if ((gd & 4095) == 0 && __hip_atomic_load(&g_abort, __ATOMIC_RELAXED, __HIP_MEMORY_SCOPE_AGENT)) break;
      }
    }
    __syncthreads();
    if (threadIdx.x == 0)
      __hip_atomic_store(&g_phase, e, __ATOMIC_RELAXED, __HIP_MEMORY_SCOPE_AGENT);
  } else {
    if (threadIdx.x == 0) {
      __hip_atomic_store(&g_slots[blockIdx.x], e, __ATOMIC_RELAXED, __HIP_MEMORY_SCOPE_AGENT);
      int gd = 0;
      while (__hip_atomic_load(&g_phase, __ATOMIC_RELAXED, __HIP_MEMORY_SCOPE_AGENT) < e) {
        __builtin_amdgcn_s_sleep(1);
        if (++gd > (1 << 24)) { __hip_atomic_store(&g_abort, 1, __ATOMIC_RELAXED, __HIP_MEMORY_SCOPE_AGENT); break; }
        if ((gd & 4095) == 0 && __hip_atomic_load(&g_abort, __ATOMIC_RELAXED, __HIP_MEMORY_SCOPE_AGENT)) break;
      }
    }
    __syncthreads();
  }
}

// ---------------- 8-value x 64-lane butterfly reduce (EXACT R2) --------------
__device__ __forceinline__ float wave_reduce8(const float (&acc)[8], int lane) {
  float a0, a1, a2, a3;
  {
    bool hi = lane & 1;
    float s0 = hi ? acc[0] : acc[1], s1 = hi ? acc[2] : acc[3];
    float s2 = hi ? acc[4] : acc[5], s3 = hi ? acc[6] : acc[7];
    float r0 = __shfl_xor(s0, 1), r1 = __shfl_xor(s1, 1);
    float r2 = __shfl_xor(s2, 1), r3 = __shfl_xor(s3, 1);
    a0 = (hi ? acc[1] : acc[0]) + r0;  a1 = (hi ? acc[3] : acc[2]) + r1;
    a2 = (hi ? acc[5] : acc[4]) + r2;  a3 = (hi ? acc[7] : acc[6]) + r3;
  }
  float b0, b1;
  {
    bool hi = lane & 2;
    float s0 = hi ? a0 : a1, s1 = hi ? a2 : a3;
    float r0 = __shfl_xor(s0, 2), r1 = __shfl_xor(s1, 2);
    b0 = (hi ? a1 : a0) + r0;  b1 = (hi ? a3 : a2) + r1;
  }
  float f;
  {
    bool hi = lane & 4;
    float s = hi ? b0 : b1;
    float r = __shfl_xor(s, 4);
    f = (hi ? b1 : b0) + r;
  }
  f += __shfl_xor(f, 8);  f += __shfl_xor(f, 16);  f += __shfl_xor(f, 32);
  return f;
}

// ---------------- staging (raw or with LayerNorm) into LDS ------------------
__device__ __forceinline__ void stage_in(float (*sx)[520], const float* __restrict__ g,
                                         bool doLN, const float* __restrict__ lw,
                                         const float* __restrict__ lb, float* __restrict__ wb) {
  const int tid = threadIdx.x;
  {
    vf4 v0, v1, v2, v3;
    ld4x4_sc(g + 4 * tid, g + 4 * tid + 1024, g + 4 * tid + 2048, g + 4 * tid + 3072,
             v0, v1, v2, v3);
    int f4 = tid;        *(vf4*)&sx[f4 >> 7][(f4 & 127) << 2] = v0;
    f4 = tid + 256;      *(vf4*)&sx[f4 >> 7][(f4 & 127) << 2] = v1;
    f4 = tid + 512;      *(vf4*)&sx[f4 >> 7][(f4 & 127) << 2] = v2;
    f4 = tid + 768;      *(vf4*)&sx[f4 >> 7][(f4 & 127) << 2] = v3;
  }
  __syncthreads();
  if (doLN) {
    const int lane = tid & 63, wv = tid >> 6;
#pragma unroll
    for (int rr = 0; rr < 2; ++rr) {
      int b = wv + 4 * rr;
      float vals[8]; float sm = 0.f;
#pragma unroll
      for (int j = 0; j < 8; ++j) { vals[j] = sx[b][lane + 64 * j]; sm += vals[j]; }
#pragma unroll
      for (int o = 32; o; o >>= 1) sm += __shfl_xor(sm, o);
      float mu = sm * (1.f / 512.f);
      float s2 = 0.f;
#pragma unroll
      for (int j = 0; j < 8; ++j) { float d = vals[j] - mu; s2 += d * d; }
#pragma unroll
      for (int o = 32; o; o >>= 1) s2 += __shfl_xor(s2, o);
      float rstd = 1.f / sqrtf(s2 * (1.f / 512.f) + 1e-5f);
#pragma unroll
      for (int j = 0; j < 8; ++j) {
        int c = lane + 64 * j;
        sx[b][c] = (vals[j] - mu) * rstd * lw[c] + lb[c];
      }
    }
    __syncthreads();
  }
  if (wb && blockIdx.x == 0) {
#pragma unroll
    for (int q = 0; q < 4; ++q) {
      int f4 = tid + 256 * q;
      vf4 w = *(vf4*)&sx[f4 >> 7][(f4 & 127) << 2];
      st4_sc(wb + 4 * f4, w);
    }
  }
}

// ---------------- generic K=512 GEMV stage ----------------------------------
template <int MODE>
__device__ __forceinline__ void gemv512(float (*sx)[520], const float* __restrict__ W,
                                        const float* __restrict__ bias, int rpb,
                                        float* __restrict__ out, const float* __restrict__ res,
                                        int l, int t, float* __restrict__ outd) {
  const int lane = threadIdx.x & 63, wv = threadIdx.x >> 6;
  const int r0 = blockIdx.x * rpb;
  for (int rr = wv; rr < rpb; rr += 4) {
    const int r = r0 + rr;
    const float* wr = W + (size_t)r * 512;
    float acc[8] = {0, 0, 0, 0, 0, 0, 0, 0};
#pragma unroll
    for (int j = 0; j < 8; ++j) {
      float w = wr[lane + 64 * j];
#pragma unroll
      for (int b = 0; b < 8; ++b) acc[b] += w * sx[b][lane + 64 * j];
    }
    float f = wave_reduce8(acc, lane);
    if (lane < 8) {
      const int b = lane;
      float v = f + bias[r];
      if constexpr (MODE == 0) {
        if (r < 512)       st_sc(&out[b * 512 + r], v);
        else if (r < 1024) st_sc(&g_kc[(((size_t)l * 8 + b) * T1 + t) * 512 + (r - 512)], v);
        else               st_sc(&g_vc[(((size_t)l * 8 + b) * T1 + t) * 512 + (r - 1024)], v);
      } else if constexpr (MODE == 1) {
        float rv = ld_sc(&res[b * 512 + r]);
        st_sc(&out[b * 512 + r], v + rv);
      } else if constexpr (MODE == 2) {
        st_sc(&out[b * 512 + r], v);
      } else if constexpr (MODE == 3) {
        st_sc(&out[b * 2048 + r], 0.5f * v * (1.f + erff(v * 0.70710678118654752f)));
      } else {
        st_sc(&g_logits[b * VOC + r], v);
        outd[((size_t)b * 32 + t) * VOC + r] = v;
      }
    }
  }
}

// ---------------- FF2: K=2048 GEMV -------------------------------------------
__device__ __forceinline__ void stage_h(float (*sb)[2052]) {
  const int tid = threadIdx.x;
#pragma unroll
  for (int q2 = 0; q2 < 4; ++q2) {
    vf4 a, b, c, d;
    const float* base = g_h + 4 * tid + 4096 * q2;
    ld4x4_sc(base, base + 1024, base + 2048, base + 3072, a, b, c, d);
    int f4 = tid + 256 * (4 * q2 + 0); *(vf4*)&sb[f4 >> 9][(f4 & 511) << 2] = a;
    f4 = tid + 256 * (4 * q2 + 1);     *(vf4*)&sb[f4 >> 9][(f4 & 511) << 2] = b;
    f4 = tid + 256 * (4 * q2 + 2);     *(vf4*)&sb[f4 >> 9][(f4 & 511) << 2] = c;
    f4 = tid + 256 * (4 * q2 + 3);     *(vf4*)&sb[f4 >> 9][(f4 & 511) << 2] = d;
  }
}

__device__ __forceinline__ void gemvH(float (*sb)[2052], const float* __restrict__ W,
                                      const float* __restrict__ bias,
                                      const float* __restrict__ res, float* __restrict__ out) {
  const int lane = threadIdx.x & 63, wv = threadIdx.x >> 6;
  const int r0 = blockIdx.x * 8;
  for (int rr = wv; rr < 8; rr += 4) {
    const int r = r0 + rr;
    const float* wr = W + (size_t)r * 2048;
    float acc[8] = {0, 0, 0, 0, 0, 0, 0, 0};
#pragma unroll 8
    for (int j = 0; j < 32; ++j) {
      float w = wr[lane + 64 * j];
#pragma unroll
      for (int b = 0; b < 8; ++b) acc[b] += w * sb[b][lane + 64 * j];
    }
    float f = wave_reduce8(acc, lane);
    if (lane < 8) {
      float rv = ld_sc(&res[lane * 512 + r]);
      st_sc(&out[lane * 512 + r], f + bias[r] + rv);
    }
  }
}

// ---------------- persistent decode kernel ----------------------------------
struct DecP {
  const float *mem, *emb, *pe, *saw, *sab, *sow, *sob, *caw, *cab, *cow, *cob,
              *lnw, *lnb, *f1w, *f1b, *f2w, *f2b, *cw, *cb;
  float* out;
};

__global__ __launch_bounds__(NT) void k_decode(DecP P) {
  __shared__ float smem[8 * 2052];
  float (*sx)[520] = (float(*)[520])smem;
  float (*sb)[2052] = (float(*)[2052])smem;
  __shared__ float s_p[336];
  __shared__ float s_w[4][2];
  __shared__ float s_pv[4][64];
  __shared__ int   s_int[2];

  const int tid = threadIdx.x, bid = blockIdx.x;
  const int lane = tid & 63, wv = tid >> 6;
  int e = 0;

  // INIT: x0 = pe[0] + emb[SOS]*sqrt(D); tok[0]=SOS
  if (bid < 8) {
    int b = bid;
#pragma unroll
    for (int q = 0; q < 2; ++q) {
      int c = tid + 256 * q;
      st_sc(&g_x[b * 512 + c], P.pe[c] + P.emb[2 * 512 + c] * SQD);
    }
    if (tid == 0) st_sci(&g_tok[b * T1], 2);
  }
  gbar(++e);

  for (int t = 0; t < 32; ++t) {
    for (int l = 0; l < NL; ++l) {
      // ---- A: self-attn QKV projection (input LN for l>0 fused here) ----
      {
        const float* lw = (l > 0) ? P.lnw + ((l - 1) * 3 + 2) * 512 : P.lnw;
        const float* lb = (l > 0) ? P.lnb + ((l - 1) * 3 + 2) * 512 : P.lnb;
        stage_in(sx, (l == 0) ? g_x : g_y, l > 0, lw, lb, (l > 0) ? g_x : nullptr);
        gemv512<0>(sx, P.saw + (size_t)l * 1536 * 512, P.sab + l * 1536, 24, g_q, nullptr, l, t, nullptr);
      }
      gbar(++e);

      // ---- B: self-attention (keys 0..t), one wave per (b,h) ----
      if (bid < 64 && wv == 0) {
        int b = bid >> 3, h = bid & 7;
        s_p[lane] = ld_sc(&g_q[b * 512 + h * 64 + lane]);
        asm volatile("s_waitcnt lgkmcnt(0)" ::: "memory");
        __builtin_amdgcn_sched_barrier(0);
        float sc = -3.4e38f;
        if (lane <= t) {
          const float4* kr = (const float4*)&g_kc[(((size_t)l * 8 + b) * T1 + lane) * 512 + h * 64];
          float s = 0.f;
#pragma unroll
          for (int d4 = 0; d4 < 16; ++d4) {
            float4 kv = kr[d4];
            s += s_p[d4 * 4 + 0] * kv.x + s_p[d4 * 4 + 1] * kv.y +
                 s_p[d4 * 4 + 2] * kv.z + s_p[d4 * 4 + 3] * kv.w;
          }
          sc = s * 0.125f;
        }
        float m = sc;
#pragma unroll
        for (int o = 32; o; o >>= 1) m = fmaxf(m, __shfl_xor(m, o));
        float ex = (lane <= t) ? expf(sc - m) : 0.f;
        float sum = ex;
#pragma unroll
        for (int o = 32; o; o >>= 1) sum += __shfl_xor(sum, o);
        s_p[64 + lane] = ex / sum;
        asm volatile("s_waitcnt lgkmcnt(0)" ::: "memory");
        __builtin_amdgcn_sched_barrier(0);
        float o = 0.f;
        for (int j = 0; j <= t; ++j)
          o += s_p[64 + j] * g_vc[(((size_t)l * 8 + b) * T1 + j) * 512 + h * 64 + lane];
        st_sc(&g_att[b * 512 + h * 64 + lane], o);
      }
      gbar(++e);

      // ---- C: self-attn out-proj + residual(x) ----
      if (bid < 64) {
        stage_in(sx, g_att, false, nullptr, nullptr, nullptr);
        gemv512<1>(sx, P.sow + (size_t)l * 512 * 512, P.sob + l * 512, 8, g_y, g_x, l, t, nullptr);
      }
      gbar(++e);

      // ---- D: LN1 + cross-attn Q projection (writes x2 = LN(y)) ----
      if (bid < 64) {
        stage_in(sx, g_y, true, P.lnw + (l * 3 + 0) * 512, P.lnb + (l * 3 + 0) * 512, g_x2);
        gemv512<2>(sx, P.caw + (size_t)l * 1536 * 512, P.cab + l * 1536, 8, g_q, nullptr, l, t, nullptr);
      }
      gbar(++e);

      // ---- E: cross-attention over 256 memory keys, block per (b,h) ----
      if (bid < 64) {
        int b = bid >> 3, h = bid & 7;
        if (tid < 64) s_p[tid] = ld_sc(&g_q[b * 512 + h * 64 + tid]);
        __syncthreads();
        int m0 = wv * 64 + lane;
        const float4* kr = (const float4*)&g_memk[((size_t)l * 2048 + b * 256 + m0) * 512 + h * 64];
        float s = 0.f;
#pragma unroll
        for (int d4 = 0; d4 < 16; ++d4) {
          float4 kv = kr[d4];
          s += s_p[d4 * 4 + 0] * kv.x + s_p[d4 * 4 + 1] * kv.y +
               s_p[d4 * 4 + 2] * kv.z + s_p[d4 * 4 + 3] * kv.w;
        }
        s *= 0.125f;
        float m = s;
#pragma unroll
        for (int o = 32; o; o >>= 1) m = fmaxf(m, __shfl_xor(m, o));
        if (lane == 0) s_w[wv][0] = m;
        __syncthreads();
        float M = fmaxf(fmaxf(s_w[0][0], s_w[1][0]), fmaxf(s_w[2][0], s_w[3][0]));
        float ex = expf(s - M);
        float sum = ex;
#pragma unroll
        for (int o = 32; o; o >>= 1) sum += __shfl_xor(sum, o);
        if (lane == 0) s_w[wv][1] = sum;
        __syncthreads();
        float S = s_w[0][1] + s_w[1][1] + s_w[2][1] + s_w[3][1];
        s_p[64 + m0] = ex / S;
        __syncthreads();
        float o = 0.f;
        const float* vbase = &g_memv[((size_t)l * 2048 + b * 256) * 512 + h * 64];
        for (int j = 0; j < 64; ++j) {
          int mm = wv * 64 + j;
          o += s_p[64 + mm] * vbase[(size_t)mm * 512 + lane];
        }
        s_pv[wv][lane] = o;
        __syncthreads();
        if (wv == 0) {
          float tot = s_pv[0][lane] + s_pv[1][lane] + s_pv[2][lane] + s_pv[3][lane];
          st_sc(&g_att[b * 512 + h * 64 + lane], tot);
        }
      }
      gbar(++e);

      // ---- F: cross-attn out-proj + residual(x2) ----
      if (bid < 64) {
        stage_in(sx, g_att, false, nullptr, nullptr, nullptr);
        gemv512<1>(sx, P.cow + (size_t)l * 512 * 512, P.cob + l * 512, 8, g_y, g_x2, l, t, nullptr);
      }
      gbar(++e);

      // ---- G: LN2 + FF1 + GELU (writes x2 = LN(y)) ----
      {
        stage_in(sx, g_y, true, P.lnw + (l * 3 + 1) * 512, P.lnb + (l * 3 + 1) * 512, g_x2);
        gemv512<3>(sx, P.f1w + (size_t)l * 2048 * 512, P.f1b + l * 2048, 32, g_h, nullptr, l, t, nullptr);
      }
      gbar(++e);

      // ---- H: FF2 + residual(x2) ----
      if (bid < 64) {
        stage_h(sb);
        __syncthreads();
        gemvH(sb, P.f2w + (size_t)l * 512 * 2048, P.f2b + l * 512, g_x2, g_y);
      }
      gbar(++e);
    }

    // ---- CLF: final LN + classifier ----
    if (bid < 16) {
      stage_in(sx, g_y, true, P.lnw + (5 * 3 + 2) * 512, P.lnb + (5 * 3 + 2) * 512, nullptr);
      gemv512<4>(sx, P.cw, P.cb, 5, nullptr, nullptr, 0, t, P.out);
    }
    gbar(++e);

    // ---- J: argmax (first-max tie-break) + next-token embedding ----
    if (bid < 8) {
      int b = bid;
      if (wv == 0) {
        const float* lp = g_logits + b * VOC;
        float v1 = ld_sc(lp + lane);
        int i1 = lane;
        if (lane < 16) {
          float v2 = ld_sc(lp + 64 + lane);
          if (v2 > v1) { v1 = v2; i1 = 64 + lane; }
        }
#pragma unroll
        for (int o = 32; o; o >>= 1) {
          float ov = __shfl_xor(v1, o);
          int oi = __shfl_xor(i1, o);
          if (ov > v1 || (ov == v1 && oi < i1)) { v1 = ov; i1 = oi; }
        }
        if (lane == 0) { s_int[0] = i1; st_sci(&g_tok[b * T1 + t + 1], i1); }
      }
      __syncthreads();
      int pred = s_int[0];
#pragma unroll
      for (int q = 0; q < 2; ++q) {
        int c = tid + 256 * q;
        st_sc(&g_x[b * 512 + c], P.pe[(t + 2) * 512 + c] + P.emb[(size_t)pred * 512 + c] * SQD);
      }
    }
    gbar(++e);
  }

  // ---- sampled output: [SOS, preds...], PAD through first EOS (or idx 0) ----
  if (bid == 0 && wv == 0 && lane < 8) {
    int b = lane;
    int eos = -1;
    for (int j = 0; j < 33; ++j) {
      int tk = ld_sci(&g_tok[b * T1 + j]);
      if (tk == 1 && eos < 0) eos = j;
    }
    if (eos < 0) eos = 0;
    for (int j = 0; j < 33; ++j) {
      int tk = ld_sci(&g_tok[b * T1 + j]);
      P.out[20480 + b * 33 + j] = (j <= eos) ? 0.f : (float)tk;
    }
  }
}

// ---------------- host entry -------------------------------------------------
extern "C" void kernel_launch(void* const* d_in, const int* in_sizes, int n_in,
                              void* d_out, int out_size, void* d_ws, size_t ws_size,
                              hipStream_t stream) {
  (void)in_sizes; (void)n_in; (void)d_ws; (void)ws_size; (void)out_size;
  const float* mem = (const float*)d_in[0];
  const float* emb = (const float*)d_in[1];
  const float* pe  = (const float*)d_in[2];
  const float* saw = (const float*)d_in[3];
  const float* sab = (const float*)d_in[4];
  const float* sow = (const float*)d_in[5];
  const float* sob = (const float*)d_in[6];
  const float* caw = (const float*)d_in[7];
  const float* cab = (const float*)d_in[8];
  const float* cow = (const float*)d_in[9];
  const float* cob = (const float*)d_in[10];
  const float* lnw = (const float*)d_in[11];
  const float* lnb = (const float*)d_in[12];
  const float* f1w = (const float*)d_in[13];
  const float* f1b = (const float*)d_in[14];
  const float* f2w = (const float*)d_in[15];
  const float* f2b = (const float*)d_in[16];
  const float* cw  = (const float*)d_in[17];
  const float* cb  = (const float*)d_in[18];

  hipLaunchKernelGGL(k_init, dim3(1), dim3(256), 0, stream);
  hipLaunchKernelGGL(k_memkv, dim3(384), dim3(256), 0, stream, mem, caw, cab);
  DecP P{mem, emb, pe, saw, sab, sow, sob, caw, cab, cow, cob,
         lnw, lnb, f1w, f1b, f2w, f2b, cw, cb, (float*)d_out};
  hipLaunchKernelGGL(k_decode, dim3(NBLK), dim3(NT), 0, stream, P);
}

// Round 11
// 8998.890 us; speedup vs baseline: 5.2374x; 2.8035x over previous
//
#include <hip/hip_runtime.h>
#include <math.h>

constexpr int T1 = 33, NL = 6, VOC = 80;
constexpr float SQD = 22.62741699796952f;  // sqrt(512)

// ---------------- device state ----------------------------------------------
__device__ float g_memk[(size_t)NL * 2048 * 512];   // [l][b*256+m][512]
__device__ float g_memv[(size_t)NL * 2048 * 512];
__device__ float g_kc[(size_t)NL * 8 * T1 * 512];
__device__ float g_vc[(size_t)NL * 8 * T1 * 512];
__device__ float g_x[8 * 512], g_x2[8 * 512], g_y[8 * 512], g_q[8 * 512], g_att[8 * 512];
__device__ float g_h[8 * 2048];
__device__ int   g_tok[8 * T1];

struct DecP {
  const float *mem, *emb, *pe, *saw, *sab, *sow, *sob, *caw, *cab, *cow, *cob,
              *lnw, *lnb, *f1w, *f1b, *f2w, *f2b, *cw, *cb;
  float* out;
};

// ---------------- memK/memV precompute (EXACT R2/R7 code) --------------------
__global__ __launch_bounds__(256) void k_memkv(const float* __restrict__ mem,
                                               const float* __restrict__ caw,
                                               const float* __restrict__ cab) {
  __shared__ float mlds[128][34];
  __shared__ float wlds[256][34];
  const int tid = threadIdx.x;
  const int l = blockIdx.x / 64, rem = blockIdx.x % 64;
  const int mt = rem >> 2, rt = rem & 3;
  const float* wbase = caw + (size_t)l * 1536 * 512 + (size_t)512 * 512;

  float acc[8][16];
#pragma unroll
  for (int i = 0; i < 8; ++i)
#pragma unroll
    for (int j = 0; j < 16; ++j) acc[i][j] = 0.f;

  const int tm = tid >> 4, tr = tid & 15;

  for (int kb = 0; kb < 16; ++kb) {
    __syncthreads();
    {
      int row = tid >> 1, half = tid & 1;
      const float2* src = (const float2*)(mem + (size_t)(mt * 128 + row) * 512 + kb * 32 + half * 16);
      float2* dst = (float2*)&mlds[row][half * 16];
#pragma unroll
      for (int q = 0; q < 8; ++q) dst[q] = src[q];
    }
    {
      int c2 = (tid & 15) * 2, rb = tid >> 4;
#pragma unroll
      for (int q = 0; q < 16; ++q) {
        int row = rb + 16 * q;
        *(float2*)&wlds[row][c2] =
            *(const float2*)(wbase + (size_t)(rt * 256 + row) * 512 + kb * 32 + c2);
      }
    }
    __syncthreads();
#pragma unroll 4
    for (int k2 = 0; k2 < 16; ++k2) {
      float2 mv[8];
#pragma unroll
      for (int i = 0; i < 8; ++i) mv[i] = *(const float2*)&mlds[tm * 8 + i][2 * k2];
#pragma unroll
      for (int j = 0; j < 16; ++j) {
        float2 w2 = *(const float2*)&wlds[tr + 16 * j][2 * k2];
#pragma unroll
        for (int i = 0; i < 8; ++i) acc[i][j] += mv[i].x * w2.x + mv[i].y * w2.y;
      }
    }
  }
#pragma unroll
  for (int i = 0; i < 8; ++i) {
    int mrow = mt * 128 + tm * 8 + i;
#pragma unroll
    for (int j = 0; j < 16; ++j) {
      int r = rt * 256 + tr + 16 * j;
      float v = acc[i][j] + cab[l * 1536 + 512 + r];
      if (r < 512) g_memk[((size_t)l * 2048 + mrow) * 512 + r] = v;
      else         g_memv[((size_t)l * 2048 + mrow) * 512 + (r - 512)] = v;
    }
  }
}

// ---------------- 8-value x 64-lane butterfly reduce (EXACT R1) --------------
__device__ __forceinline__ float wave_reduce8(const float (&acc)[8], int lane) {
  float a0, a1, a2, a3;
  {
    bool hi = lane & 1;
    float s0 = hi ? acc[0] : acc[1], s1 = hi ? acc[2] : acc[3];
    float s2 = hi ? acc[4] : acc[5], s3 = hi ? acc[6] : acc[7];
    float r0 = __shfl_xor(s0, 1), r1 = __shfl_xor(s1, 1);
    float r2 = __shfl_xor(s2, 1), r3 = __shfl_xor(s3, 1);
    a0 = (hi ? acc[1] : acc[0]) + r0;  a1 = (hi ? acc[3] : acc[2]) + r1;
    a2 = (hi ? acc[5] : acc[4]) + r2;  a3 = (hi ? acc[7] : acc[6]) + r3;
  }
  float b0, b1;
  {
    bool hi = lane & 2;
    float s0 = hi ? a0 : a1, s1 = hi ? a2 : a3;
    float r0 = __shfl_xor(s0, 2), r1 = __shfl_xor(s1, 2);
    b0 = (hi ? a1 : a0) + r0;  b1 = (hi ? a3 : a2) + r1;
  }
  float f;
  {
    bool hi = lane & 4;
    float s = hi ? b0 : b1;
    float r = __shfl_xor(s, 4);
    f = (hi ? b1 : b0) + r;
  }
  f += __shfl_xor(f, 8);  f += __shfl_xor(f, 16);  f += __shfl_xor(f, 32);
  return f;
}

// ---------------- staging (raw or with LayerNorm) into LDS (EXACT R1) --------
__device__ __forceinline__ void stage_in(float (*sx)[520], const float* __restrict__ g,
                                         bool doLN, const float* __restrict__ lw,
                                         const float* __restrict__ lb, float* __restrict__ wb) {
  const int tid = threadIdx.x;
#pragma unroll
  for (int q = 0; q < 4; ++q) {
    int f4 = tid + 256 * q;
    int b = f4 >> 7, c = (f4 & 127) << 2;
    float4 v = ((const float4*)g)[f4];
    *(float4*)&sx[b][c] = v;
  }
  __syncthreads();
  if (doLN) {
    const int lane = tid & 63, wv = tid >> 6;
#pragma unroll
    for (int rr = 0; rr < 2; ++rr) {
      int b = wv + 4 * rr;
      float vals[8]; float sm = 0.f;
#pragma unroll
      for (int j = 0; j < 8; ++j) { vals[j] = sx[b][lane + 64 * j]; sm += vals[j]; }
#pragma unroll
      for (int o = 32; o; o >>= 1) sm += __shfl_xor(sm, o);
      float mu = sm * (1.f / 512.f);
      float s2 = 0.f;
#pragma unroll
      for (int j = 0; j < 8; ++j) { float d = vals[j] - mu; s2 += d * d; }
#pragma unroll
      for (int o = 32; o; o >>= 1) s2 += __shfl_xor(s2, o);
      float rstd = 1.f / sqrtf(s2 * (1.f / 512.f) + 1e-5f);
#pragma unroll
      for (int j = 0; j < 8; ++j) {
        int c = lane + 64 * j;
        sx[b][c] = (vals[j] - mu) * rstd * lw[c] + lb[c];
      }
    }
    __syncthreads();
  }
  if (wb && blockIdx.x == 0) {
#pragma unroll
    for (int q = 0; q < 4; ++q) {
      int f4 = tid + 256 * q;
      int b = f4 >> 7, c = (f4 & 127) << 2;
      ((float4*)wb)[f4] = *(float4*)&sx[b][c];
    }
  }
}

// ---------------- generic K=512 GEMV stage (EXACT R1) ------------------------
template <int MODE>
__device__ __forceinline__ void gemv512(float (*sx)[520], const float* __restrict__ W,
                                        const float* __restrict__ bias, int rpb,
                                        float* __restrict__ out, const float* __restrict__ res,
                                        int l, int t) {
  const int lane = threadIdx.x & 63, wv = threadIdx.x >> 6;
  const int r0 = blockIdx.x * rpb;
  for (int rr = wv; rr < rpb; rr += 4) {
    const int r = r0 + rr;
    const float* wr = W + (size_t)r * 512;
    float acc[8] = {0, 0, 0, 0, 0, 0, 0, 0};
#pragma unroll
    for (int j = 0; j < 8; ++j) {
      float w = wr[lane + 64 * j];
#pragma unroll
      for (int b = 0; b < 8; ++b) acc[b] += w * sx[b][lane + 64 * j];
    }
    float f = wave_reduce8(acc, lane);
    if (lane < 8) {
      const int b = lane;
      float v = f + bias[r];
      if constexpr (MODE == 0) {
        if (r < 512)       out[b * 512 + r] = v;
        else if (r < 1024) g_kc[(((size_t)l * 8 + b) * T1 + t) * 512 + (r - 512)] = v;
        else               g_vc[(((size_t)l * 8 + b) * T1 + t) * 512 + (r - 1024)] = v;
      } else if constexpr (MODE == 1) {
        out[b * 512 + r] = v + res[b * 512 + r];
      } else if constexpr (MODE == 2) {
        out[b * 512 + r] = v;
      } else {
        out[b * 2048 + r] = 0.5f * v * (1.f + erff(v * 0.70710678118654752f));
      }
    }
  }
}

// ---------------- FF2 helpers (EXACT R1) -------------------------------------
__device__ __forceinline__ void stage_h(float (*sb)[2052]) {
  const int tid = threadIdx.x;
#pragma unroll
  for (int q = 0; q < 16; ++q) {
    int f4 = tid + 256 * q;
    int b = f4 >> 9, c = (f4 & 511) << 2;
    *(float4*)&sb[b][c] = ((const float4*)g_h)[f4];
  }
}

__device__ __forceinline__ void gemvH(float (*sb)[2052], const float* __restrict__ W,
                                      const float* __restrict__ bias,
                                      const float* __restrict__ res, float* __restrict__ out) {
  const int lane = threadIdx.x & 63, wv = threadIdx.x >> 6;
  const int r0 = blockIdx.x * 8;
  for (int rr = wv; rr < 8; rr += 4) {
    const int r = r0 + rr;
    const float* wr = W + (size_t)r * 2048;
    float acc[8] = {0, 0, 0, 0, 0, 0, 0, 0};
#pragma unroll 8
    for (int j = 0; j < 32; ++j) {
      float w = wr[lane + 64 * j];
#pragma unroll
      for (int b = 0; b < 8; ++b) acc[b] += w * sb[b][lane + 64 * j];
    }
    float f = wave_reduce8(acc, lane);
    if (lane < 8) out[lane * 512 + r] = f + bias[r] + res[lane * 512 + r];
  }
}

// ---------------- per-phase kernels ------------------------------------------
__global__ __launch_bounds__(256) void k_start(DecP P) {
  int b = blockIdx.x;
#pragma unroll
  for (int q = 0; q < 2; ++q) {
    int c = threadIdx.x + 256 * q;
    g_x[b * 512 + c] = P.pe[c] + P.emb[2 * 512 + c] * SQD;
  }
  if (threadIdx.x == 0) g_tok[b * T1] = 2;
}

// A: (LN(prev l2) if l>0) + QKV projection. grid 192
__global__ __launch_bounds__(256) void k_A(DecP P, int l, int t) {
  __shared__ float sx[8][520];
  const float* lw = (l > 0) ? P.lnw + ((l - 1) * 3 + 2) * 512 : P.lnw;
  const float* lb = (l > 0) ? P.lnb + ((l - 1) * 3 + 2) * 512 : P.lnb;
  stage_in(sx, (l == 0) ? g_x : g_y, l > 0, lw, lb, (l > 0) ? g_x : nullptr);
  gemv512<0>(sx, P.saw + (size_t)l * 1536 * 512, P.sab + l * 1536, 8, g_q, nullptr, l, t);
}

// B: self-attention over keys 0..t. grid 64 x 64 threads
__global__ __launch_bounds__(64) void k_B(DecP P, int l, int t) {
  __shared__ float s_p[128];
  const int lane = threadIdx.x;
  const int b = blockIdx.x >> 3, h = blockIdx.x & 7;
  s_p[lane] = g_q[b * 512 + h * 64 + lane];
  asm volatile("s_waitcnt lgkmcnt(0)" ::: "memory");
  __builtin_amdgcn_sched_barrier(0);
  float sc = -3.4e38f;
  if (lane <= t) {
    const float4* kr = (const float4*)&g_kc[(((size_t)l * 8 + b) * T1 + lane) * 512 + h * 64];
    float s = 0.f;
#pragma unroll
    for (int d4 = 0; d4 < 16; ++d4) {
      float4 kv = kr[d4];
      s += s_p[d4 * 4 + 0] * kv.x + s_p[d4 * 4 + 1] * kv.y +
           s_p[d4 * 4 + 2] * kv.z + s_p[d4 * 4 + 3] * kv.w;
    }
    sc = s * 0.125f;
  }
  float m = sc;
#pragma unroll
  for (int o = 32; o; o >>= 1) m = fmaxf(m, __shfl_xor(m, o));
  float ex = (lane <= t) ? expf(sc - m) : 0.f;
  float sum = ex;
#pragma unroll
  for (int o = 32; o; o >>= 1) sum += __shfl_xor(sum, o);
  s_p[64 + lane] = ex / sum;
  asm volatile("s_waitcnt lgkmcnt(0)" ::: "memory");
  __builtin_amdgcn_sched_barrier(0);
  float o = 0.f;
  for (int j = 0; j <= t; ++j)
    o += s_p[64 + j] * g_vc[(((size_t)l * 8 + b) * T1 + j) * 512 + h * 64 + lane];
  g_att[b * 512 + h * 64 + lane] = o;
}

// C: self out-proj + residual(g_x). grid 64
__global__ __launch_bounds__(256) void k_C(DecP P, int l) {
  __shared__ float sx[8][520];
  stage_in(sx, g_att, false, nullptr, nullptr, nullptr);
  gemv512<1>(sx, P.sow + (size_t)l * 512 * 512, P.sob + l * 512, 8, g_y, g_x, l, 0);
}

// D: LN(l,0) + cross-attn Q proj (block 0 writes g_x2 = LN(y)). grid 64
__global__ __launch_bounds__(256) void k_D(DecP P, int l) {
  __shared__ float sx[8][520];
  stage_in(sx, g_y, true, P.lnw + (l * 3 + 0) * 512, P.lnb + (l * 3 + 0) * 512, g_x2);
  gemv512<2>(sx, P.caw + (size_t)l * 1536 * 512, P.cab + l * 1536, 8, g_q, nullptr, l, 0);
}

// E: cross-attention over 256 memory keys. grid 64
__global__ __launch_bounds__(256) void k_E(DecP P, int l) {
  __shared__ float s_p[336];
  __shared__ float s_w[4][2];
  __shared__ float s_pv[4][64];
  const int tid = threadIdx.x;
  const int lane = tid & 63, wv = tid >> 6;
  const int b = blockIdx.x >> 3, h = blockIdx.x & 7;
  if (tid < 64) s_p[tid] = g_q[b * 512 + h * 64 + tid];
  __syncthreads();
  int m0 = wv * 64 + lane;
  const float4* kr = (const float4*)&g_memk[((size_t)l * 2048 + b * 256 + m0) * 512 + h * 64];
  float s = 0.f;
#pragma unroll
  for (int d4 = 0; d4 < 16; ++d4) {
    float4 kv = kr[d4];
    s += s_p[d4 * 4 + 0] * kv.x + s_p[d4 * 4 + 1] * kv.y +
         s_p[d4 * 4 + 2] * kv.z + s_p[d4 * 4 + 3] * kv.w;
  }
  s *= 0.125f;
  float m = s;
#pragma unroll
  for (int o = 32; o; o >>= 1) m = fmaxf(m, __shfl_xor(m, o));
  if (lane == 0) s_w[wv][0] = m;
  __syncthreads();
  float M = fmaxf(fmaxf(s_w[0][0], s_w[1][0]), fmaxf(s_w[2][0], s_w[3][0]));
  float ex = expf(s - M);
  float sum = ex;
#pragma unroll
  for (int o = 32; o; o >>= 1) sum += __shfl_xor(sum, o);
  if (lane == 0) s_w[wv][1] = sum;
  __syncthreads();
  float S = s_w[0][1] + s_w[1][1] + s_w[2][1] + s_w[3][1];
  s_p[64 + m0] = ex / S;
  __syncthreads();
  float o = 0.f;
  const float* vbase = &g_memv[((size_t)l * 2048 + b * 256) * 512 + h * 64];
  for (int j = 0; j < 64; ++j) {
    int mm = wv * 64 + j;
    o += s_p[64 + mm] * vbase[(size_t)mm * 512 + lane];
  }
  s_pv[wv][lane] = o;
  __syncthreads();
  if (wv == 0) {
    float tot = s_pv[0][lane] + s_pv[1][lane] + s_pv[2][lane] + s_pv[3][lane];
    g_att[b * 512 + h * 64 + lane] = tot;
  }
}

// F: cross out-proj + residual(g_x2). grid 64
__global__ __launch_bounds__(256) void k_F(DecP P, int l) {
  __shared__ float sx[8][520];
  stage_in(sx, g_att, false, nullptr, nullptr, nullptr);
  gemv512<1>(sx, P.cow + (size_t)l * 512 * 512, P.cob + l * 512, 8, g_y, g_x2, l, 0);
}

// G: LN(l,1) + FF1 + GELU (block 0 writes g_x2 = LN(y)). grid 256
__global__ __launch_bounds__(256) void k_G(DecP P, int l) {
  __shared__ float sx[8][520];
  stage_in(sx, g_y, true, P.lnw + (l * 3 + 1) * 512, P.lnb + (l * 3 + 1) * 512, g_x2);
  gemv512<3>(sx, P.f1w + (size_t)l * 2048 * 512, P.f1b + l * 2048, 8, g_h, nullptr, l, 0);
}

// H: FF2 + residual(g_x2). grid 64
__global__ __launch_bounds__(256) void k_H(DecP P, int l) {
  __shared__ float sb[8][2052];
  stage_h(sb);
  __syncthreads();
  gemvH(sb, P.f2w + (size_t)l * 512 * 2048, P.f2b + l * 512, g_x2, g_y);
}

// T: final LN + classifier + argmax + next-token embedding. grid 8
__global__ __launch_bounds__(256) void k_T(DecP P, int t) {
  __shared__ float sx[8][520];
  __shared__ float s_p[80];
  __shared__ int s_int[1];
  const int tid = threadIdx.x;
  const int lane = tid & 63, wv = tid >> 6;
  const int b = blockIdx.x;
  stage_in(sx, g_y, true, P.lnw + (5 * 3 + 2) * 512, P.lnb + (5 * 3 + 2) * 512, nullptr);
  for (int i = 0; i < 20; ++i) {
    int r = wv * 20 + i;
    const float* wr = P.cw + (size_t)r * 512;
    float a = 0.f;
#pragma unroll
    for (int j = 0; j < 8; ++j) a += wr[lane + 64 * j] * sx[b][lane + 64 * j];
#pragma unroll
    for (int o = 32; o; o >>= 1) a += __shfl_xor(a, o);
    if (lane == 0) {
      float v = a + P.cb[r];
      s_p[r] = v;
      P.out[((size_t)b * 32 + t) * VOC + r] = v;
    }
  }
  __syncthreads();
  if (wv == 0) {
    float v1 = s_p[lane];
    int i1 = lane;
    if (lane < 16) {
      float v2 = s_p[64 + lane];
      if (v2 > v1) { v1 = v2; i1 = 64 + lane; }
    }
#pragma unroll
    for (int o = 32; o; o >>= 1) {
      float ov = __shfl_xor(v1, o);
      int oi = __shfl_xor(i1, o);
      if (ov > v1 || (ov == v1 && oi < i1)) { v1 = ov; i1 = oi; }
    }
    if (lane == 0) { s_int[0] = i1; g_tok[b * T1 + t + 1] = i1; }
  }
  __syncthreads();
  int pred = s_int[0];
#pragma unroll
  for (int q = 0; q < 2; ++q) {
    int c = tid + 256 * q;
    g_x[b * 512 + c] = P.pe[(t + 2) * 512 + c] + P.emb[(size_t)pred * 512 + c] * SQD;
  }
}

// OUT: sampled sequence postprocess. grid 1 x 64
__global__ __launch_bounds__(64) void k_out(DecP P) {
  int lane = threadIdx.x;
  if (lane < 8) {
    int b = lane;
    int eos = -1;
    for (int j = 0; j < T1; ++j) {
      int tk = g_tok[b * T1 + j];
      if (tk == 1 && eos < 0) eos = j;
    }
    if (eos < 0) eos = 0;
    for (int j = 0; j < T1; ++j) {
      int tk = g_tok[b * T1 + j];
      P.out[20480 + b * T1 + j] = (j <= eos) ? 0.f : (float)tk;
    }
  }
}

// ---------------- host entry -------------------------------------------------
extern "C" void kernel_launch(void* const* d_in, const int* in_sizes, int n_in,
                              void* d_out, int out_size, void* d_ws, size_t ws_size,
                              hipStream_t stream) {
  (void)in_sizes; (void)n_in; (void)d_ws; (void)ws_size; (void)out_size;
  const float* mem = (const float*)d_in[0];
  const float* emb = (const float*)d_in[1];
  const float* pe  = (const float*)d_in[2];
  const float* saw = (const float*)d_in[3];
  const float* sab = (const float*)d_in[4];
  const float* sow = (const float*)d_in[5];
  const float* sob = (const float*)d_in[6];
  const float* caw = (const float*)d_in[7];
  const float* cab = (const float*)d_in[8];
  const float* cow = (const float*)d_in[9];
  const float* cob = (const float*)d_in[10];
  const float* lnw = (const float*)d_in[11];
  const float* lnb = (const float*)d_in[12];
  const float* f1w = (const float*)d_in[13];
  const float* f1b = (const float*)d_in[14];
  const float* f2w = (const float*)d_in[15];
  const float* f2b = (const float*)d_in[16];
  const float* cw  = (const float*)d_in[17];
  const float* cb  = (const float*)d_in[18];

  DecP P{mem, emb, pe, saw, sab, sow, sob, caw, cab, cow, cob,
         lnw, lnb, f1w, f1b, f2w, f2b, cw, cb, (float*)d_out};

  hipLaunchKernelGGL(k_start, dim3(8), dim3(256), 0, stream, P);
  hipLaunchKernelGGL(k_memkv, dim3(384), dim3(256), 0, stream, mem, caw, cab);

  for (int t = 0; t < 32; ++t) {
    for (int l = 0; l < NL; ++l) {
      hipLaunchKernelGGL(k_A, dim3(192), dim3(256), 0, stream, P, l, t);
      hipLaunchKernelGGL(k_B, dim3(64), dim3(64), 0, stream, P, l, t);
      hipLaunchKernelGGL(k_C, dim3(64), dim3(256), 0, stream, P, l);
      hipLaunchKernelGGL(k_D, dim3(64), dim3(256), 0, stream, P, l);
      hipLaunchKernelGGL(k_E, dim3(64), dim3(256), 0, stream, P, l);
      hipLaunchKernelGGL(k_F, dim3(64), dim3(256), 0, stream, P, l);
      hipLaunchKernelGGL(k_G, dim3(256), dim3(256), 0, stream, P, l);
      hipLaunchKernelGGL(k_H, dim3(64), dim3(256), 0, stream, P, l);
    }
    hipLaunchKernelGGL(k_T, dim3(8), dim3(256), 0, stream, P, t);
  }
  hipLaunchKernelGGL(k_out, dim3(1), dim3(64), 0, stream, P);
}